// Round 1
// baseline (195.491 us; speedup 1.0000x reference)
//
#include <hip/hip_runtime.h>
#include <hip/hip_bf16.h>
#include <stdint.h>

#define B_DIM 64
#define S_DIM 4096
#define C_DIM 128
#define TARGET_LEN 1000

// ---------------------------------------------------------------------------
// Kernel 1: lengths[b] = number of True entries in mask row b.
// The mask is a prefix sequence mask (first `len` entries True), so popcount
// equals the reference's (S - argmax(reversed)) computation.
// Mask dtype from the harness is unknown for bool arrays -> runtime sniff:
// row 0 has length >= S/2, so its first 4 elements are all True:
//   bytes [01 01 01 01] -> 1-byte bool
//   bytes [01 00 00 00] -> int32 ones
//   bytes [00 00 80 3F] -> float32 1.0f
// ---------------------------------------------------------------------------
__global__ void lengths_kernel(const void* __restrict__ mask_raw,
                               int* __restrict__ lengths) {
    const int b = blockIdx.x;
    const int tid = threadIdx.x;

    // dtype sniff (uniform across all threads; L2-cached broadcast load)
    const uint32_t first = *(const uint32_t*)mask_raw;

    int cnt = 0;
    if (first == 0x01010101u) {
        // 1-byte bool
        const uint8_t* m = (const uint8_t*)mask_raw + (size_t)b * S_DIM;
        for (int i = tid; i < S_DIM; i += blockDim.x) cnt += (m[i] != 0);
    } else if (first == 0x3F800000u) {
        // float32 0.0/1.0
        const float* m = (const float*)mask_raw + (size_t)b * S_DIM;
        for (int i = tid; i < S_DIM; i += blockDim.x) cnt += (m[i] != 0.0f);
    } else {
        // int32 0/1 (default per harness "integer -> const int*")
        const int* m = (const int*)mask_raw + (size_t)b * S_DIM;
        for (int i = tid; i < S_DIM; i += blockDim.x) cnt += (m[i] != 0);
    }

    // wave (64-lane) reduce, then cross-wave via LDS (256 threads = 4 waves)
    for (int off = 32; off > 0; off >>= 1) cnt += __shfl_down(cnt, off);

    __shared__ int sdata[4];
    const int wave = tid >> 6;
    const int lane = tid & 63;
    if (lane == 0) sdata[wave] = cnt;
    __syncthreads();
    if (tid == 0) {
        lengths[b] = sdata[0] + sdata[1] + sdata[2] + sdata[3];
    }
}

// ---------------------------------------------------------------------------
// Kernel 2: bilinear resize, one thread per (b, l, c4) float4.
// Coordinate math mirrors the reference in exact IEEE f32 (no FMA
// contraction: a fused (l+0.5)*scale-0.5 could flip floor() at an integer
// boundary and pick the wrong source row).
// ---------------------------------------------------------------------------
__global__ void resize_kernel(const float* __restrict__ in,   // [B, S, C]
                              const int* __restrict__ lengths,
                              float* __restrict__ out) {       // [B, L, C]
    const int C4 = C_DIM / 4;  // 32 float4 per row
    int idx = blockIdx.x * blockDim.x + threadIdx.x;           // [0, B*L*C4)
    const int total = B_DIM * TARGET_LEN * C4;
    if (idx >= total) return;

    const int c4 = idx & (C4 - 1);
    const int bl = idx >> 5;            // b * TARGET_LEN + l
    const int l  = bl % TARGET_LEN;
    const int b  = bl / TARGET_LEN;

    const int len = lengths[b];
    const float scale = __fdiv_rn((float)len, (float)TARGET_LEN);
    // src = (l + 0.5)*scale - 0.5, exact f32, no contraction
    const float t   = __fadd_rn((float)l, 0.5f);
    const float src = __fsub_rn(__fmul_rn(t, scale), 0.5f);

    const int maxi = len - 1;
    int lo = (int)floorf(src);
    int hi = (int)ceilf(src);
    lo = min(max(lo, 0), maxi);
    hi = min(max(hi, 0), maxi);
    const float w = __fsub_rn(src, (float)lo);

    const size_t base = (size_t)b * S_DIM * C_DIM;
    const float4 xlo = *(const float4*)(in + base + (size_t)lo * C_DIM + c4 * 4);
    const float4 xhi = *(const float4*)(in + base + (size_t)hi * C_DIM + c4 * 4);

    float4 r;
    r.x = __fadd_rn(xlo.x, __fmul_rn(__fsub_rn(xhi.x, xlo.x), w));
    r.y = __fadd_rn(xlo.y, __fmul_rn(__fsub_rn(xhi.y, xlo.y), w));
    r.z = __fadd_rn(xlo.z, __fmul_rn(__fsub_rn(xhi.z, xlo.z), w));
    r.w = __fadd_rn(xlo.w, __fmul_rn(__fsub_rn(xhi.w, xlo.w), w));

    *(float4*)(out + (size_t)bl * C_DIM + c4 * 4) = r;
}

extern "C" void kernel_launch(void* const* d_in, const int* in_sizes, int n_in,
                              void* d_out, int out_size, void* d_ws, size_t ws_size,
                              hipStream_t stream) {
    const float* in   = (const float*)d_in[0];
    const void*  mask = d_in[1];
    float* out = (float*)d_out;
    int* lengths = (int*)d_ws;

    lengths_kernel<<<B_DIM, 256, 0, stream>>>(mask, lengths);

    const int total = B_DIM * TARGET_LEN * (C_DIM / 4);  // 2,048,000
    resize_kernel<<<(total + 255) / 256, 256, 0, stream>>>(in, lengths, out);
}

// Round 2
// 190.977 us; speedup vs baseline: 1.0236x; 1.0236x over previous
//
#include <hip/hip_runtime.h>
#include <hip/hip_bf16.h>
#include <stdint.h>

#define B_DIM 64
#define S_DIM 4096
#define C_DIM 128
#define TARGET_LEN 1000
#define ROWS_PER_BLOCK 8   // 125 * 8 = 1000

// ---------------------------------------------------------------------------
// Fused kernel: each block handles (b = blockIdx.y, rows chunk = blockIdx.x).
// Step 1: block cooperatively recomputes lengths[b] = popcount(mask row b).
//         Mask is 256 KB total -> L2-resident, so the 125x redundancy per b
//         is nearly free (4 KB vectorized read per block for bool masks).
// Step 2: 256 threads = 8 output rows x 32 float4 columns of bilinear resize.
// Coordinate math is exact IEEE f32 with no FMA contraction (a fused
// (l+0.5)*scale-0.5 could flip floor() at a boundary and pick the wrong row).
// ---------------------------------------------------------------------------
__global__ __launch_bounds__(256) void fused_resize_kernel(
    const float* __restrict__ in,      // [B, S, C]
    const void* __restrict__ mask_raw, // [B, S] bool/int/float (sniffed)
    float* __restrict__ out) {         // [B, L, C]
    const int b     = blockIdx.y;
    const int chunk = blockIdx.x;
    const int tid   = threadIdx.x;

    // ---- Step 1: row length via popcount of the prefix mask ----
    // dtype sniff: row 0 has length >= S/2, so first 4 elems are all True:
    //   0x01010101 -> 1-byte bool, 0x3F800000 -> f32 1.0, else int32 ones
    const uint32_t first = *(const uint32_t*)mask_raw;

    int cnt = 0;
    if (first == 0x01010101u) {
        // 1-byte bool: 4096 B/row, one uint4 (16 bools) per thread
        const uint4* m = (const uint4*)((const uint8_t*)mask_raw + (size_t)b * S_DIM);
        uint4 v = m[tid];
        cnt = __popc(v.x) + __popc(v.y) + __popc(v.z) + __popc(v.w);
    } else if (first == 0x3F800000u) {
        // float32 0.0/1.0: 16 KB/row, four float4 per thread
        const float4* m = (const float4*)((const float*)mask_raw + (size_t)b * S_DIM);
        #pragma unroll
        for (int k = 0; k < 4; ++k) {
            float4 v = m[tid + k * 256];
            cnt += (v.x != 0.0f) + (v.y != 0.0f) + (v.z != 0.0f) + (v.w != 0.0f);
        }
    } else {
        // int32 0/1: 16 KB/row, four uint4 per thread (popc counts 1-words)
        const uint4* m = (const uint4*)((const int*)mask_raw + (size_t)b * S_DIM);
        #pragma unroll
        for (int k = 0; k < 4; ++k) {
            uint4 v = m[tid + k * 256];
            cnt += __popc(v.x) + __popc(v.y) + __popc(v.z) + __popc(v.w);
        }
    }

    // wave64 reduce, then cross-wave via LDS (4 waves)
    #pragma unroll
    for (int off = 32; off > 0; off >>= 1) cnt += __shfl_down(cnt, off);

    __shared__ int sdata[4];
    __shared__ int s_len;
    const int wave = tid >> 6;
    const int lane = tid & 63;
    if (lane == 0) sdata[wave] = cnt;
    __syncthreads();
    if (tid == 0) s_len = sdata[0] + sdata[1] + sdata[2] + sdata[3];
    __syncthreads();
    const int len = s_len;

    // ---- Step 2: bilinear resize, one float4 per thread ----
    const int c4 = tid & 31;              // 32 float4 per row
    const int l  = chunk * ROWS_PER_BLOCK + (tid >> 5);

    const float scale = __fdiv_rn((float)len, (float)TARGET_LEN);
    const float t     = __fadd_rn((float)l, 0.5f);
    const float src   = __fsub_rn(__fmul_rn(t, scale), 0.5f);

    const int maxi = len - 1;
    int lo = (int)floorf(src);
    int hi = (int)ceilf(src);
    lo = min(max(lo, 0), maxi);
    hi = min(max(hi, 0), maxi);
    const float w = __fsub_rn(src, (float)lo);

    const size_t base = (size_t)b * S_DIM * C_DIM;
    const float4 xlo = *(const float4*)(in + base + (size_t)lo * C_DIM + c4 * 4);
    const float4 xhi = *(const float4*)(in + base + (size_t)hi * C_DIM + c4 * 4);

    float4 r;
    r.x = __fadd_rn(xlo.x, __fmul_rn(__fsub_rn(xhi.x, xlo.x), w));
    r.y = __fadd_rn(xlo.y, __fmul_rn(__fsub_rn(xhi.y, xlo.y), w));
    r.z = __fadd_rn(xlo.z, __fmul_rn(__fsub_rn(xhi.z, xlo.z), w));
    r.w = __fadd_rn(xlo.w, __fmul_rn(__fsub_rn(xhi.w, xlo.w), w));

    const size_t obase = ((size_t)b * TARGET_LEN + l) * C_DIM + c4 * 4;
    *(float4*)(out + obase) = r;
}

extern "C" void kernel_launch(void* const* d_in, const int* in_sizes, int n_in,
                              void* d_out, int out_size, void* d_ws, size_t ws_size,
                              hipStream_t stream) {
    const float* in   = (const float*)d_in[0];
    const void*  mask = d_in[1];
    float* out = (float*)d_out;

    dim3 grid(TARGET_LEN / ROWS_PER_BLOCK, B_DIM);  // (125, 64)
    fused_resize_kernel<<<grid, 256, 0, stream>>>(in, mask, out);
}